// Round 4
// baseline (535.927 us; speedup 1.0000x reference)
//
#include <hip/hip_runtime.h>
#include <hip/hip_bf16.h>
#include <stdint.h>

#define NE 500000
#define NN 100000
#define HD 128

typedef __bf16 bf16x8 __attribute__((ext_vector_type(8)));
typedef float f32x4 __attribute__((ext_vector_type(4)));
typedef unsigned short u16x4 __attribute__((ext_vector_type(4)));

#define MFMA16(a, b, c) __builtin_amdgcn_mfma_f32_16x16x32_bf16(a, b, c, 0, 0, 0)

__device__ __forceinline__ uint16_t f2bf(float f) {
  union { float f; uint32_t u; } v; v.f = f;
  uint32_t r = (v.u + 0x7FFFu + ((v.u >> 16) & 1u)) >> 16;
  return (uint16_t)r;
}

// Generic f32 -> bf16 (RNE) converter, 4 elems/thread, grid-stride.
// nt loads: inputs are read exactly once here; keep L2/L3 clean for xb.
__global__ void cvt_f32_bf16(const float* __restrict__ src,
                             uint16_t* __restrict__ dst, int n4) {
  int i = blockIdx.x * blockDim.x + threadIdx.x;
  int stride = gridDim.x * blockDim.x;
  for (; i < n4; i += stride) {
    f32x4 v = __builtin_nontemporal_load(reinterpret_cast<const f32x4*>(src) + i);
    u16x4 o;
    o.x = f2bf(v.x); o.y = f2bf(v.y); o.z = f2bf(v.z); o.w = f2bf(v.w);
    reinterpret_cast<u16x4*>(dst)[i] = o;
  }
}

// Detect whether index buffers are int64 (harness doc says int32; reference
// says int64 — be robust to both). If indices are little-endian int64 with
// 0 <= v < 2^31, every odd 32-bit word is 0. For genuine int32 random
// indices in [0,1e5), 1024 consecutive odd words all being zero is
// impossible. flag=1 -> int64, flag=0 -> int32.
__global__ void detect_i64(const int* __restrict__ p, int* __restrict__ flag) {
  __shared__ int any_nonzero;
  if (threadIdx.x == 0) any_nonzero = 0;
  __syncthreads();
  for (int i = threadIdx.x; i < 1024; i += blockDim.x)
    if (p[2 * i + 1] != 0) any_nonzero = 1;
  __syncthreads();
  if (threadIdx.x == 0) *flag = (any_nonzero ? 0 : 1);
}

__device__ __forceinline__ int load_idx(const int* p, int e, bool i64) {
  return i64 ? (int)(reinterpret_cast<const long long*>(p)[e]) : p[e];
}

// One wave = 32 edges. Layer1: D1[e][h] = sum_k Xcat[e][k]*W1[h][k]
// (A = Xcat rows gathered from global, B = W1 rows -> B[k][n]=W1[n][k]).
// Bias+ReLU -> bf16 -> wave-private LDS [32][136].
// Layer2 (swapped): D2[h2][e] = sum_k W2[h2][k]*H1[e][k]
// -> lane holds 4 consecutive h2 for one edge -> float4 nt stores.
__global__ __launch_bounds__(256) void edge_mlp(
    const int* __restrict__ src, const int* __restrict__ dst,
    const uint16_t* __restrict__ xb, const uint16_t* __restrict__ w1b,
    const uint16_t* __restrict__ w2b, const float* __restrict__ b1,
    const float* __restrict__ b2, const int* __restrict__ i64flag,
    float* __restrict__ out) {
  __shared__ uint16_t h1s[4][32 * 136];

  const int lane = threadIdx.x & 63;
  const int wid  = threadIdx.x >> 6;
  const int g = lane >> 4;      // lane group 0..3 (k-chunk)
  const int r = lane & 15;      // row/col within fragment

  const int wave_global = blockIdx.x * 4 + wid;
  const int ebase = wave_global * 32;
  if (ebase >= NE) return;

  const bool i64 = (__builtin_amdgcn_readfirstlane(*i64flag) != 0);

  // Node indices for this wave's 32 edges (two 16-row m-tiles).
  const int s0 = load_idx(src, ebase + r, i64);
  const int s1 = load_idx(src, ebase + 16 + r, i64);
  const int d0 = load_idx(dst, ebase + r, i64);
  const int d1 = load_idx(dst, ebase + 16 + r, i64);

  // Per-lane A-fragment base pointers (8 bf16 per k-chunk: elem = 32*ks + 8*g).
  const uint16_t* pxs0 = xb + (size_t)s0 * HD + 8 * g;
  const uint16_t* pxs1 = xb + (size_t)s1 * HD + 8 * g;
  const uint16_t* pxd0 = xb + (size_t)d0 * HD + 8 * g;
  const uint16_t* pxd1 = xb + (size_t)d1 * HD + 8 * g;

  f32x4 acc[2][8];
#pragma unroll
  for (int mt = 0; mt < 2; ++mt)
#pragma unroll
    for (int ht = 0; ht < 8; ++ht) acc[mt][ht] = (f32x4)(0.0f);

  // ---- Layer 1: K = 256 (src 0..127, dst 128..255), 8 k-steps of 32 ----
#pragma unroll
  for (int ks = 0; ks < 8; ++ks) {
    bf16x8 a0, a1;
    if (ks < 4) {
      a0 = *reinterpret_cast<const bf16x8*>(pxs0 + 32 * ks);
      a1 = *reinterpret_cast<const bf16x8*>(pxs1 + 32 * ks);
    } else {
      a0 = *reinterpret_cast<const bf16x8*>(pxd0 + 32 * (ks - 4));
      a1 = *reinterpret_cast<const bf16x8*>(pxd1 + 32 * (ks - 4));
    }
#pragma unroll
    for (int ht = 0; ht < 8; ++ht) {
      // B[k][n] = W1[16*ht + r][32*ks + 8*g + i]
      bf16x8 b = *reinterpret_cast<const bf16x8*>(
          w1b + (16 * ht + r) * 256 + 32 * ks + 8 * g);
      acc[0][ht] = MFMA16(a0, b, acc[0][ht]);
      acc[1][ht] = MFMA16(a1, b, acc[1][ht]);
    }
  }

  // ---- Bias + ReLU -> bf16 -> wave-private LDS tile [e_local][h], ld=136 ----
  uint16_t* myh1 = h1s[wid];
#pragma unroll
  for (int ht = 0; ht < 8; ++ht) {
    const float bias = b1[16 * ht + r];
#pragma unroll
    for (int mt = 0; mt < 2; ++mt) {
#pragma unroll
      for (int i = 0; i < 4; ++i) {
        // D layout (m89): col = lane&15 = r (h), row = 4*g + i (edge in tile)
        float v = acc[mt][ht][i] + bias;
        v = fmaxf(v, 0.0f);
        const int e_local = 16 * mt + 4 * g + i;
        myh1[e_local * 136 + 16 * ht + r] = f2bf(v);
      }
    }
  }
  // Wave-private LDS tile: RAW within one wave; compiler inserts lgkmcnt waits.

  // ---- Layer 2: D2 = W2 * H1^T, K = 128, 4 k-steps ----
  f32x4 acc2[8][2];
#pragma unroll
  for (int mt = 0; mt < 8; ++mt)
#pragma unroll
    for (int nt = 0; nt < 2; ++nt) acc2[mt][nt] = (f32x4)(0.0f);

#pragma unroll
  for (int ks = 0; ks < 4; ++ks) {
    // B[k][e] = H1[16*nt + r][32*ks + 8*g + i]
    bf16x8 bb0 = *reinterpret_cast<const bf16x8*>(
        myh1 + (0 + r) * 136 + 32 * ks + 8 * g);
    bf16x8 bb1 = *reinterpret_cast<const bf16x8*>(
        myh1 + (16 + r) * 136 + 32 * ks + 8 * g);
#pragma unroll
    for (int mt = 0; mt < 8; ++mt) {
      // A[m][k] = W2[16*mt + r][32*ks + 8*g + i]
      bf16x8 aw = *reinterpret_cast<const bf16x8*>(
          w2b + (16 * mt + r) * 128 + 32 * ks + 8 * g);
      acc2[mt][0] = MFMA16(aw, bb0, acc2[mt][0]);
      acc2[mt][1] = MFMA16(aw, bb1, acc2[mt][1]);
    }
  }

  // ---- Bias + store: lane holds h2 = 16*mt + 4*g + 0..3 for edge 16*nt+r ----
  // out is 256 MB write-once: non-temporal to avoid evicting xb from L2/L3.
#pragma unroll
  for (int mt = 0; mt < 8; ++mt) {
    const f32x4 b4 = *reinterpret_cast<const f32x4*>(b2 + 16 * mt + 4 * g);
#pragma unroll
    for (int nt = 0; nt < 2; ++nt) {
      const int e = ebase + 16 * nt + r;
      f32x4 v = acc2[mt][nt] + b4;
      __builtin_nontemporal_store(
          v, reinterpret_cast<f32x4*>(out + (size_t)e * HD + 16 * mt + 4 * g));
    }
  }
}

extern "C" void kernel_launch(void* const* d_in, const int* in_sizes, int n_in,
                              void* d_out, int out_size, void* d_ws, size_t ws_size,
                              hipStream_t stream) {
  const float* x   = (const float*)d_in[0];
  const int*   src = (const int*)d_in[1];
  const int*   dst = (const int*)d_in[2];
  const float* W1  = (const float*)d_in[3];
  const float* b1  = (const float*)d_in[4];
  const float* W2  = (const float*)d_in[5];
  const float* b2  = (const float*)d_in[6];
  float* out = (float*)d_out;

  // Workspace layout: [flag:int][pad to 256B][xb 25.6MB][w1b 64KB][w2b 32KB]
  int* i64flag  = (int*)d_ws;
  uint16_t* xb  = (uint16_t*)((char*)d_ws + 256);
  uint16_t* w1b = xb + (size_t)NN * HD;
  uint16_t* w2b = w1b + (size_t)HD * 2 * HD;

  detect_i64<<<1, 256, 0, stream>>>(src, i64flag);

  // bf16 conversions (write all bytes we later read; ws is re-poisoned each call)
  cvt_f32_bf16<<<2048, 256, 0, stream>>>(x, xb, NN * HD / 4);
  cvt_f32_bf16<<<32, 256, 0, stream>>>(W1, w1b, HD * 2 * HD / 4);
  cvt_f32_bf16<<<16, 256, 0, stream>>>(W2, w2b, HD * HD / 4);

  const int n_waves = NE / 32;                     // 15625 exactly
  const int n_blocks = (n_waves + 3) / 4;          // 3907
  edge_mlp<<<n_blocks, 256, 0, stream>>>(src, dst, xb, w1b, w2b, b1, b2,
                                         i64flag, out);
}